// Round 2
// baseline (390.156 us; speedup 1.0000x reference)
//
#include <hip/hip_runtime.h>

// ---------------- problem constants ----------------
#define NFFT    2048
#define HOPSZ   512
#define BATCH   8
#define TFRAMES 2048
#define FBINS   1025
#define OUTLEN  1048064           // HOP*(T-1)
#define TOTALP  1050112           // NFFT + HOP*(T-1)
#define KPAD    2080              // 2050 padded to mult of 32
#define MROWS   16384             // BATCH*TFRAMES
#define KSTEPS  (KPAD / 32)       // 65

typedef float  f32x4  __attribute__((ext_vector_type(4)));
typedef __bf16 bf16x8 __attribute__((ext_vector_type(8)));

typedef __attribute__((address_space(3))) void       lds_void;
typedef const __attribute__((address_space(1))) void gmem_void;

__device__ __forceinline__ unsigned short f2bf(float f) {
    unsigned u = __float_as_uint(f);
    u += 0x7fffu + ((u >> 16) & 1u);       // round-to-nearest-even
    return (unsigned short)(u >> 16);
}

// ---------------- W2[ks][a][32]: K-tiled bf16 IDFT weights ------------------
// W[k,a]: k<1025  ->  c_k * cos(2*pi*k*a/N)/N * win[a]
//         k<2050  -> -c_b * sin(2*pi*b*a/N)/N * win[a],  b=k-1025 ; else 0
__global__ void build_w(unsigned short* __restrict__ W2) {
    int kc = blockIdx.x * 256 + threadIdx.x;     // 8-elem chunk index
    if (kc >= KPAD / 8) return;
    int a  = blockIdx.y;
    int k0 = kc * 8;
    float win   = 0.5f - 0.5f * cospif((float)a * (1.0f / 1024.0f));
    float scale = win * (1.0f / 2048.0f);
    unsigned short v[8];
    #pragma unroll
    for (int j = 0; j < 8; ++j) {
        int   k = k0 + j;
        float f = 0.0f;
        if (k < 1025) {
            int   m = (k * a) & 2047;
            float c = (k == 0 || k == 1024) ? 1.0f : 2.0f;
            f = c * cospif((float)m * (1.0f / 1024.0f)) * scale;
        } else if (k < 2050) {
            int   bb = k - 1025;
            int   m  = (bb * a) & 2047;
            float c  = (bb == 0 || bb == 1024) ? 1.0f : 2.0f;
            f = -c * sinpif((float)m * (1.0f / 1024.0f)) * scale;
        }
        v[j] = f2bf(f);
    }
    *(uint4*)(W2 + ((size_t)(k0 >> 5) * NFFT + a) * 32 + (k0 & 31)) = *(const uint4*)v;
}

// ---------------- X2[ks][bt][32] = K-tiled [real | imag | 0] bf16 -----------
__global__ void conv_x(const float* __restrict__ re, const float* __restrict__ im,
                       unsigned short* __restrict__ X2) {
    int kc = blockIdx.x * 256 + threadIdx.x;
    if (kc >= KPAD / 8) return;
    int bt = blockIdx.y;
    int k0 = kc * 8;
    unsigned short v[8];
    #pragma unroll
    for (int j = 0; j < 8; ++j) {
        int   k = k0 + j;
        float f = 0.0f;
        if (k < 1025)      f = re[(size_t)bt * FBINS + k];
        else if (k < 2050) f = im[(size_t)bt * FBINS + (k - 1025)];
        v[j] = f2bf(f);
    }
    *(uint4*)(X2 + ((size_t)(k0 >> 5) * MROWS + bt) * 32 + (k0 & 31)) = *(const uint4*)v;
}

// ---------------- 1 / window_sumsquare --------------------------------------
__global__ void build_invws(float* __restrict__ iw) {
    int p = blockIdx.x * 256 + threadIdx.x;
    if (p >= TOTALP) return;
    int tmax = p >> 9;            if (tmax > TFRAMES - 1) tmax = TFRAMES - 1;
    int tmin = (p - 1536) >> 9;   if (tmin < 0) tmin = 0;
    float s = 0.0f;
    for (int t = tmin; t <= tmax; ++t) {
        int   a = p - (t << 9);
        float w = 0.5f - 0.5f * cospif((float)a * (1.0f / 1024.0f));
        s += w * w;
    }
    s = fmaxf(s, 1e-8f);
    iw[p] = 1.0f / s;
}

// ---------------- GEMM (bf16 MFMA, m97 structure) + fused overlap-add -------
// 128x128 tile, BK=32, 4 waves 2x2, each wave 64x64 = 4x4 frags of 16x16x32.
// Staging: global_load_lds dwordx4, linear LDS [128][32] (no pad — required).
#define BM  128
#define BN  128
#define BK  32

__global__ __launch_bounds__(256) void gemm_ola(
    const unsigned short* __restrict__ X2,  // [KSTEPS][MROWS][32]
    const unsigned short* __restrict__ W2,  // [KSTEPS][NFFT][32]
    const float*          __restrict__ iw,  // [TOTALP]
    float*                __restrict__ out) // [BATCH][OUTLEN]
{
    __shared__ __align__(16) unsigned short As[BM * BK];
    __shared__ __align__(16) unsigned short Bs[BN * BK];

    const int tid  = threadIdx.x;
    const int lane = tid & 63;
    const int w    = tid >> 6;
    const int wr   = w >> 1, wc = w & 1;
    const int l16  = lane & 15, lhi = lane >> 4;

    const int colBase = blockIdx.x * BN;    // a      (fastest-varying: share A-panel, L2-local OLA)
    const int rowBase = blockIdx.y * BM;    // bt

    f32x4 acc[4][4];
    #pragma unroll
    for (int i = 0; i < 4; ++i)
        #pragma unroll
        for (int j = 0; j < 4; ++j)
            acc[i][j] = f32x4{0.f, 0.f, 0.f, 0.f};

    for (int ks = 0; ks < KSTEPS; ++ks) {
        // contiguous 8 KB panels
        const unsigned short* aP = X2 + ((size_t)ks * MROWS + rowBase) * BK;
        const unsigned short* bP = W2 + ((size_t)ks * NFFT  + colBase) * BK;
        __builtin_amdgcn_global_load_lds((gmem_void*)(aP + tid * 8),
                                         (lds_void*)(As + tid * 8),        16, 0, 0);
        __builtin_amdgcn_global_load_lds((gmem_void*)(aP + (256 + tid) * 8),
                                         (lds_void*)(As + (256 + tid) * 8), 16, 0, 0);
        __builtin_amdgcn_global_load_lds((gmem_void*)(bP + tid * 8),
                                         (lds_void*)(Bs + tid * 8),        16, 0, 0);
        __builtin_amdgcn_global_load_lds((gmem_void*)(bP + (256 + tid) * 8),
                                         (lds_void*)(Bs + (256 + tid) * 8), 16, 0, 0);
        __syncthreads();   // compiler drains vmcnt(0) here (known m97 structural stall)

        bf16x8 af[4], bfr[4];
        #pragma unroll
        for (int mi = 0; mi < 4; ++mi)
            af[mi] = *(const bf16x8*)(As + (wr * 64 + mi * 16 + l16) * BK + lhi * 8);
        #pragma unroll
        for (int ni = 0; ni < 4; ++ni)
            bfr[ni] = *(const bf16x8*)(Bs + (wc * 64 + ni * 16 + l16) * BK + lhi * 8);
        #pragma unroll
        for (int mi = 0; mi < 4; ++mi)
            #pragma unroll
            for (int ni = 0; ni < 4; ++ni)
                acc[mi][ni] = __builtin_amdgcn_mfma_f32_16x16x32_bf16(
                    af[mi], bfr[ni], acc[mi][ni], 0, 0, 0);
        __syncthreads();   // protect LDS before next stage
    }

    // fused overlap-add: frame t, intra-frame offset a -> sample p = t*512 + a
    #pragma unroll
    for (int mi = 0; mi < 4; ++mi) {
        const int grBase = rowBase + wr * 64 + mi * 16 + lhi * 4;
        #pragma unroll
        for (int ni = 0; ni < 4; ++ni) {
            const int gc = colBase + wc * 64 + ni * 16 + l16;
            #pragma unroll
            for (int r = 0; r < 4; ++r) {
                const int row = grBase + r;          // bt
                const int t   = row & (TFRAMES - 1);
                const int b   = row >> 11;
                const int p   = t * HOPSZ + gc;
                const int n   = p - (NFFT / 2);      // center=True slice
                if (n >= 0 && n < OUTLEN)
                    unsafeAtomicAdd(out + (size_t)b * OUTLEN + n,
                                    acc[mi][ni][r] * iw[p]);
            }
        }
    }
}

// ---------------- launch -----------------------------------------------------
extern "C" void kernel_launch(void* const* d_in, const int* in_sizes, int n_in,
                              void* d_out, int out_size, void* d_ws, size_t ws_size,
                              hipStream_t stream) {
    const float* re = (const float*)d_in[0];
    const float* im = (const float*)d_in[1];
    float* out = (float*)d_out;

    char* ws = (char*)d_ws;
    unsigned short* X2   = (unsigned short*)(ws);                        // 16384*2080*2 = 68,157,440 B
    unsigned short* W2   = (unsigned short*)(ws + 68157440);             //  2048*2080*2 =  8,519,680 B
    float*          invw = (float*)        (ws + 68157440 + 8519680);    //  1050112*4   =  4,200,448 B

    hipMemsetAsync(d_out, 0, (size_t)out_size * sizeof(float), stream);

    build_w    <<<dim3(2, NFFT),  256, 0, stream>>>(W2);
    conv_x     <<<dim3(2, MROWS), 256, 0, stream>>>(re, im, X2);
    build_invws<<<dim3(4102),     256, 0, stream>>>(invw);
    gemm_ola   <<<dim3(NFFT / BN, MROWS / BM), 256, 0, stream>>>(X2, W2, invw, out);
}

// Round 3
// 239.975 us; speedup vs baseline: 1.6258x; 1.6258x over previous
//
#include <hip/hip_runtime.h>

// ---------------- problem constants ----------------
#define NFFT    2048
#define HOPSZ   512
#define BATCH   8
#define TFRAMES 2048
#define FBINS   1025
#define OUTLEN  1048064           // HOP*(T-1)
#define TOTALP  1050112           // NFFT + HOP*(T-1)
#define KPAD    2080              // 1056 (even class) + 1024 (odd class)
#define KEVEN   1056              // [Re even 512 | Im even 512 | Re1024 | Im1024 | pad 30]
#define MROWS   16384             // BATCH*TFRAMES
#define KSTEPS  65
#define KS_E    33                // even-class K-steps (33*32 = 1056)
#define NCOLS   1024              // radix-2: compute a in [0,1024) only

typedef float  f32x4  __attribute__((ext_vector_type(4)));
typedef __bf16 bf16x8 __attribute__((ext_vector_type(8)));

typedef __attribute__((address_space(3))) void       lds_void;
typedef const __attribute__((address_space(1))) void gmem_void;

__device__ __forceinline__ unsigned short f2bf(float f) {
    unsigned u = __float_as_uint(f);
    u += 0x7fffu + ((u >> 16) & 1u);       // round-to-nearest-even
    return (unsigned short)(u >> 16);
}

// ---------------- W2[ks][a][32]: packed-K bf16 IDFT weights (NO window) -----
// k' < 1056 (even class): e=k' : e<512 -> Re bin 2e (cos); e<1024 -> Im bin
//   2(e-512) (-sin); e==1024 -> Re bin 1024; e==1025 -> Im bin 1024; else 0.
// k' >= 1056 (odd class): o=k'-1056 : o<512 -> Re bin 2o+1; else Im bin 2(o-512)+1.
__global__ void build_w(unsigned short* __restrict__ W2) {
    int kc = blockIdx.x * 256 + threadIdx.x;     // 8-elem chunk
    if (kc >= KPAD / 8) return;
    int a  = blockIdx.y;                          // [0,1024)
    int k0 = kc * 8;
    unsigned short v[8];
    #pragma unroll
    for (int j = 0; j < 8; ++j) {
        int kp = k0 + j;
        int bin; bool isSin; bool valid = true;
        if (kp < KEVEN) {
            int e = kp;
            if      (e < 512)  { bin = 2 * e;          isSin = false; }
            else if (e < 1024) { bin = 2 * (e - 512);  isSin = true;  }
            else if (e == 1024){ bin = 1024;           isSin = false; }
            else if (e == 1025){ bin = 1024;           isSin = true;  }
            else { valid = false; bin = 0; isSin = false; }
        } else {
            int o = kp - KEVEN;
            if (o < 512) { bin = 2 * o + 1;         isSin = false; }
            else         { bin = 2 * (o - 512) + 1; isSin = true;  }
        }
        float f = 0.0f;
        if (valid) {
            int   m = (bin * a) & 2047;
            float c = (bin == 0 || bin == 1024) ? 1.0f : 2.0f;
            float tr = isSin ? -sinpif((float)m * (1.0f / 1024.0f))
                             :  cospif((float)m * (1.0f / 1024.0f));
            f = c * tr * (1.0f / 2048.0f);
        }
        v[j] = f2bf(f);
    }
    *(uint4*)(W2 + ((size_t)(k0 >> 5) * NCOLS + a) * 32 + (k0 & 31)) = *(const uint4*)v;
}

// ---------------- X2[ks][bt][32]: packed-K bf16 inputs ----------------------
// One block per bt row. tid<128: Re chunks; tid>=128: Im chunks. Even/odd
// deinterleave in-register; aligned 8B stores. Spare work on lanes 0..31
// handles boundary bins + zero pad.
__global__ void conv_x(const float* __restrict__ re, const float* __restrict__ im,
                       unsigned short* __restrict__ X2) {
    const int bt  = blockIdx.x;
    const int tid = threadIdx.x;
    const bool isIm = tid >= 128;
    const int  t8   = tid & 127;                  // bins [8*t8, 8*t8+8)
    const float* src = (isIm ? im : re) + (size_t)bt * FBINS;

    float f[8];
    #pragma unroll
    for (int j = 0; j < 8; ++j) f[j] = src[t8 * 8 + j];

    unsigned short ev[4], od[4];
    #pragma unroll
    for (int i = 0; i < 4; ++i) { ev[i] = f2bf(f[2 * i]); od[i] = f2bf(f[2 * i + 1]); }

    const int e0 = (isIm ? 512 : 0) + t8 * 4;            // even-class k' (mult of 4)
    const int o0 = KEVEN + (isIm ? 512 : 0) + t8 * 4;    // odd-class  k' (mult of 4)
    *(uint2*)(X2 + ((size_t)(e0 >> 5) * MROWS + bt) * 32 + (e0 & 31)) = *(const uint2*)ev;
    *(uint2*)(X2 + ((size_t)(o0 >> 5) * MROWS + bt) * 32 + (o0 & 31)) = *(const uint2*)od;

    // extras: k'=1024 (Re bin 1024), k'=1025 (Im bin 1024), k' 1026..1055 zero
    if (tid < 30)
        X2[((size_t)((1026 + tid) >> 5) * MROWS + bt) * 32 + ((1026 + tid) & 31)] = 0;
    else if (tid == 30)
        X2[((size_t)(1024 >> 5) * MROWS + bt) * 32 + (1024 & 31)] = f2bf(re[(size_t)bt * FBINS + 1024]);
    else if (tid == 31)
        X2[((size_t)(1025 >> 5) * MROWS + bt) * 32 + (1025 & 31)] = f2bf(im[(size_t)bt * FBINS + 1024]);
}

// ---------------- 1 / window_sumsquare --------------------------------------
__global__ void build_invws(float* __restrict__ iw) {
    int p = blockIdx.x * 256 + threadIdx.x;
    if (p >= TOTALP) return;
    int tmax = p >> 9;            if (tmax > TFRAMES - 1) tmax = TFRAMES - 1;
    int tmin = (p - 1536) >> 9;   if (tmin < 0) tmin = 0;
    float s = 0.0f;
    for (int t = tmin; t <= tmax; ++t) {
        int   a = p - (t << 9);
        float w = 0.5f - 0.5f * cospif((float)a * (1.0f / 1024.0f));
        s += w * w;
    }
    s = fmaxf(s, 1e-8f);
    iw[p] = 1.0f / s;
}

// ---------------- GEMM (bf16 MFMA, radix-2) + fused overlap-add -------------
// 128x128 tile over (bt, a) with a in [0,1024). Two acc sets: E (even K class)
// and O (odd). Epilogue: col a gets (E+O)*win[a], col a+1024 gets (E-O)*(1-win[a]).
// XCD swizzle: all 8 col-tiles of a row-group share one XCD -> OLA atomics
// combine in that XCD's L2.
#define BM  128
#define BN  128
#define BK  32

__global__ __launch_bounds__(256) void gemm_ola(
    const unsigned short* __restrict__ X2,  // [KSTEPS][MROWS][32]
    const unsigned short* __restrict__ W2,  // [KSTEPS][NCOLS][32]
    const float*          __restrict__ iw,  // [TOTALP]
    float*                __restrict__ out) // [BATCH][OUTLEN]
{
    __shared__ __align__(16) unsigned short As[BM * BK];
    __shared__ __align__(16) unsigned short Bs[BN * BK];

    const int tid  = threadIdx.x;
    const int lane = tid & 63;
    const int w    = tid >> 6;
    const int wr   = w >> 1, wc = w & 1;
    const int l16  = lane & 15, lhi = lane >> 4;

    // XCD-grouping swizzle: bid = c + 8*(colTile + 8*ygrp); rowTile = ygrp*8+c
    const int bid     = blockIdx.x;
    const int c       = bid & 7;
    const int r2      = bid >> 3;
    const int colTile = r2 & 7;
    const int rowTile = ((r2 >> 3) << 3) + c;

    const int colBase = colTile * BN;    // a in [0,1024)
    const int rowBase = rowTile * BM;    // bt

    f32x4 accE[4][4], accO[4][4];
    #pragma unroll
    for (int i = 0; i < 4; ++i)
        #pragma unroll
        for (int j = 0; j < 4; ++j) {
            accE[i][j] = f32x4{0.f, 0.f, 0.f, 0.f};
            accO[i][j] = f32x4{0.f, 0.f, 0.f, 0.f};
        }

    // ---- even-class K loop (ks 0..32) -> accE ----
    for (int ks = 0; ks < KS_E; ++ks) {
        const unsigned short* aP = X2 + ((size_t)ks * MROWS + rowBase) * BK;
        const unsigned short* bP = W2 + ((size_t)ks * NCOLS + colBase) * BK;
        __builtin_amdgcn_global_load_lds((gmem_void*)(aP + tid * 8),
                                         (lds_void*)(As + tid * 8),        16, 0, 0);
        __builtin_amdgcn_global_load_lds((gmem_void*)(aP + (256 + tid) * 8),
                                         (lds_void*)(As + (256 + tid) * 8), 16, 0, 0);
        __builtin_amdgcn_global_load_lds((gmem_void*)(bP + tid * 8),
                                         (lds_void*)(Bs + tid * 8),        16, 0, 0);
        __builtin_amdgcn_global_load_lds((gmem_void*)(bP + (256 + tid) * 8),
                                         (lds_void*)(Bs + (256 + tid) * 8), 16, 0, 0);
        __syncthreads();
        bf16x8 af[4], bfr[4];
        #pragma unroll
        for (int mi = 0; mi < 4; ++mi)
            af[mi] = *(const bf16x8*)(As + (wr * 64 + mi * 16 + l16) * BK + lhi * 8);
        #pragma unroll
        for (int ni = 0; ni < 4; ++ni)
            bfr[ni] = *(const bf16x8*)(Bs + (wc * 64 + ni * 16 + l16) * BK + lhi * 8);
        #pragma unroll
        for (int mi = 0; mi < 4; ++mi)
            #pragma unroll
            for (int ni = 0; ni < 4; ++ni)
                accE[mi][ni] = __builtin_amdgcn_mfma_f32_16x16x32_bf16(
                    af[mi], bfr[ni], accE[mi][ni], 0, 0, 0);
        __syncthreads();
    }
    // ---- odd-class K loop (ks 33..64) -> accO ----
    for (int ks = KS_E; ks < KSTEPS; ++ks) {
        const unsigned short* aP = X2 + ((size_t)ks * MROWS + rowBase) * BK;
        const unsigned short* bP = W2 + ((size_t)ks * NCOLS + colBase) * BK;
        __builtin_amdgcn_global_load_lds((gmem_void*)(aP + tid * 8),
                                         (lds_void*)(As + tid * 8),        16, 0, 0);
        __builtin_amdgcn_global_load_lds((gmem_void*)(aP + (256 + tid) * 8),
                                         (lds_void*)(As + (256 + tid) * 8), 16, 0, 0);
        __builtin_amdgcn_global_load_lds((gmem_void*)(bP + tid * 8),
                                         (lds_void*)(Bs + tid * 8),        16, 0, 0);
        __builtin_amdgcn_global_load_lds((gmem_void*)(bP + (256 + tid) * 8),
                                         (lds_void*)(Bs + (256 + tid) * 8), 16, 0, 0);
        __syncthreads();
        bf16x8 af[4], bfr[4];
        #pragma unroll
        for (int mi = 0; mi < 4; ++mi)
            af[mi] = *(const bf16x8*)(As + (wr * 64 + mi * 16 + l16) * BK + lhi * 8);
        #pragma unroll
        for (int ni = 0; ni < 4; ++ni)
            bfr[ni] = *(const bf16x8*)(Bs + (wc * 64 + ni * 16 + l16) * BK + lhi * 8);
        #pragma unroll
        for (int mi = 0; mi < 4; ++mi)
            #pragma unroll
            for (int ni = 0; ni < 4; ++ni)
                accO[mi][ni] = __builtin_amdgcn_mfma_f32_16x16x32_bf16(
                    af[mi], bfr[ni], accO[mi][ni], 0, 0, 0);
        __syncthreads();
    }

    // ---- fused overlap-add epilogue ----
    #pragma unroll
    for (int ni = 0; ni < 4; ++ni) {
        const int a   = colBase + wc * 64 + ni * 16 + l16;
        const float win = 0.5f - 0.5f * cospif((float)a * (1.0f / 1024.0f));
        #pragma unroll
        for (int mi = 0; mi < 4; ++mi) {
            const int grBase = rowBase + wr * 64 + mi * 16 + lhi * 4;
            #pragma unroll
            for (int r = 0; r < 4; ++r) {
                const int row = grBase + r;          // bt
                const int t   = row & (TFRAMES - 1);
                const int b   = row >> 11;
                const int p0  = t * HOPSZ + a;
                const int n0  = p0 - (NFFT / 2);
                const float E = accE[mi][ni][r], O = accO[mi][ni][r];
                float* ob = out + (size_t)b * OUTLEN;
                if (n0 >= 0 && n0 < OUTLEN)
                    unsafeAtomicAdd(ob + n0, (E + O) * win * iw[p0]);
                const int n1 = n0 + 1024;
                if (n1 >= 0 && n1 < OUTLEN)
                    unsafeAtomicAdd(ob + n1, (E - O) * (1.0f - win) * iw[p0 + 1024]);
            }
        }
    }
}

// ---------------- launch -----------------------------------------------------
extern "C" void kernel_launch(void* const* d_in, const int* in_sizes, int n_in,
                              void* d_out, int out_size, void* d_ws, size_t ws_size,
                              hipStream_t stream) {
    const float* re = (const float*)d_in[0];
    const float* im = (const float*)d_in[1];
    float* out = (float*)d_out;

    char* ws = (char*)d_ws;
    unsigned short* X2   = (unsigned short*)(ws);                        // 65*16384*32*2 = 68,157,440 B
    unsigned short* W2   = (unsigned short*)(ws + 68157440);             // 65*1024*32*2  =  4,259,840 B
    float*          invw = (float*)        (ws + 68157440 + 4259840);    // 1050112*4     =  4,200,448 B

    hipMemsetAsync(d_out, 0, (size_t)out_size * sizeof(float), stream);

    build_w    <<<dim3(2, NCOLS), 256, 0, stream>>>(W2);
    conv_x     <<<dim3(MROWS),    256, 0, stream>>>(re, im, X2);
    build_invws<<<dim3(4102),     256, 0, stream>>>(invw);
    gemm_ola   <<<dim3((MROWS / BM) * (NCOLS / BN)), 256, 0, stream>>>(X2, W2, invw, out);
}